// Round 6
// baseline (151.001 us; speedup 1.0000x reference)
//
#include <hip/hip_runtime.h>

// out[b,n,m] = Re{ ifft2(y2) } stored as float32 [256][256][256]
//   = D + 0.0125*(-1)^(A+B)*S + kappa*(-1)^(A+B)*Re( e^{2pi i 3(n+m)/256} * T_b[n%128,m%128] )
//   T_b[u,v] = sum_{i,j} s[b,i,j] e^{+2pi i (iu+jv)/128}   (unnormalized inverse DFT)
//   kappa = (0.05+0.05^2)/65536
// D = idwtx quadrant value; per 2x2 block Haar: w = dwt(block); v = 2*shrink(w,1)-w; block' = idwt(v)

#define NB 128  // LDS row stride in complex elements: T = 128*128*8 = 131072 B exactly

__device__ __forceinline__ float fwv(float w) {
    float sh = fmaxf(fabsf(w) - 1.0f, 0.0f);
    return 2.0f * copysignf(sh, w) - w;
}

__global__ __launch_bounds__(1024) void fused_kernel(const float* __restrict__ s,
                                                     const float* __restrict__ image,
                                                     float* __restrict__ outf,
                                                     int out_floats)
{
    __shared__ float2 T[128 * NB];   // 131,072 B — nothing else in LDS

    const int tid = threadIdx.x;
    const int b   = blockIdx.x;
    const float TWO_PI = 6.2831853071795864769f;

    // --- load s with both indices bit-reversed (DIT wants bit-reversed input) ---
    const float* sb = s + (size_t)b * (128 * 128);
    for (int e = tid; e < 128 * 128; e += 1024) {
        int i = e >> 7, j = e & 127;
        int bi = (int)(__builtin_bitreverse32((unsigned)i) >> 25);
        int bj = (int)(__builtin_bitreverse32((unsigned)j) >> 25);
        T[bi * NB + bj] = make_float2(sb[e], 0.0f);
    }
    __syncthreads();

    // --- row FFTs (transform over dim j), radix-2 DIT, twiddle e^{+i ang} (inverse-DFT sign) ---
    for (int st = 0; st < 7; ++st) {
        int half = 1 << st;
        for (int bidx = tid; bidx < 8192; bidx += 1024) {
            int row = bidx >> 6;           // 0..127
            int bt  = bidx & 63;           // 0..63
            int r = bt & (half - 1);
            int g = (bt >> st) << (st + 1);
            int i0 = row * NB + g + r;
            int i1 = i0 + half;
            float ws, wc;
            __sincosf(TWO_PI * (float)r / (float)(2 << st), &ws, &wc);
            float2 x0 = T[i0], x1 = T[i1];
            float tr = wc * x1.x - ws * x1.y;
            float ti = wc * x1.y + ws * x1.x;
            T[i0] = make_float2(x0.x + tr, x0.y + ti);
            T[i1] = make_float2(x0.x - tr, x0.y - ti);
        }
        __syncthreads();
    }
    // --- column FFTs (transform over dim i) ---
    for (int st = 0; st < 7; ++st) {
        int half = 1 << st;
        for (int bidx = tid; bidx < 8192; bidx += 1024) {
            int col = bidx & 127;          // lanes -> consecutive cols (2-way max, free)
            int bt  = bidx >> 7;           // 0..63
            int r = bt & (half - 1);
            int g = (bt >> st) << (st + 1);
            int i0 = (g + r) * NB + col;
            int i1 = i0 + half * NB;
            float ws, wc;
            __sincosf(TWO_PI * (float)r / (float)(2 << st), &ws, &wc);
            float2 x0 = T[i0], x1 = T[i1];
            float tr = wc * x1.x - ws * x1.y;
            float ti = wc * x1.y + ws * x1.x;
            T[i0] = make_float2(x0.x + tr, x0.y + ti);
            T[i1] = make_float2(x0.x - tr, x0.y - ti);
        }
        __syncthreads();
    }

    // --- output phase: each quadruple (p,q) covers pixels (2p+r+128A, 2q+c+128B) ---
    const float  c0    = 0.0125f;            // 0.05/4
    const float  kappa = 0.0525f / 65536.0f; // (0.05+0.05^2)/65536
    const size_t obase = (size_t)b * 65536;  // float index of this batch's (real-only) output
    const float2* ib = (const float2*)(image + (size_t)b * 65536);  // [256 rows][128 float2]

    for (int qd = tid; qd < 4096; qd += 1024) {
        int p = qd >> 6;   // 0..63
        int q = qd & 63;   // 0..63

        // idwtx 2x2 blocks for the 4 shift-quadrants
        float D[2][2][2][2]; // [A][B][r][c]
        #pragma unroll
        for (int A = 0; A < 2; ++A) {
            #pragma unroll
            for (int Bq = 0; Bq < 2; ++Bq) {
                int P = p + 64 * A, Q = q + 64 * Bq;
                float2 t0 = ib[(2 * P) * 128 + Q];
                float2 t1 = ib[(2 * P + 1) * 128 + Q];
                float a = t0.x, bb = t0.y, cc = t1.x, dd = t1.y;
                float wll = (a + bb + cc + dd) * 0.5f;
                float wlh = (a - bb + cc - dd) * 0.5f;
                float whl = (a + bb - cc - dd) * 0.5f;
                float whh = (a - bb - cc + dd) * 0.5f;
                float vll = fwv(wll), vlh = fwv(wlh), vhl = fwv(whl), vhh = fwv(whh);
                D[A][Bq][0][0] = (vll + vlh + vhl + vhh) * 0.5f;
                D[A][Bq][0][1] = (vll - vlh + vhl - vhh) * 0.5f;
                D[A][Bq][1][0] = (vll + vlh - vhl - vhh) * 0.5f;
                D[A][Bq][1][1] = (vll - vlh - vhl + vhh) * 0.5f;
            }
        }
        // shift-combination S[r][c] = D00 - D10 - D01 + D11
        float S[2][2];
        #pragma unroll
        for (int r = 0; r < 2; ++r)
            #pragma unroll
            for (int c = 0; c < 2; ++c)
                S[r][c] = D[0][0][r][c] - D[1][0][r][c] - D[0][1][r][c] + D[1][1][r][c];

        // T values shared by all 4 quadrants: u = 2p+r (mod 128), v = 2q+c (mod 128)
        float4 trow0 = *(const float4*)&T[(2 * p) * NB + 2 * q];
        float4 trow1 = *(const float4*)&T[(2 * p + 1) * NB + 2 * q];
        float2 Tv[2][2] = { { make_float2(trow0.x, trow0.y), make_float2(trow0.z, trow0.w) },
                            { make_float2(trow1.x, trow1.y), make_float2(trow1.z, trow1.w) } };

        // Re/Im of e^{2pi i 3 t/256} at t = 2p+2q+r+c, for r+c = 0,1,2
        float2 phv[3];
        #pragma unroll
        for (int k = 0; k < 3; ++k) {
            float ps, pc;
            __sincosf((TWO_PI * 3.0f / 256.0f) * (float)(2 * p + 2 * q + k), &ps, &pc);
            phv[k] = make_float2(pc, ps);
        }

        #pragma unroll
        for (int A = 0; A < 2; ++A) {
            #pragma unroll
            for (int Bq = 0; Bq < 2; ++Bq) {
                // phase picks up (-1)^(A+B) from the 128-shift; S-combination sign is (-1)^(A xor B)
                float kq  = ((A + Bq) & 1) ? -kappa : kappa;
                float sS  = ((A ^ Bq) & 1) ? -c0 : c0;
                int nrow = 2 * p + 128 * A;
                int mcol = 2 * q + 128 * Bq;
                #pragma unroll
                for (int r = 0; r < 2; ++r) {
                    float2 ph0 = phv[r];
                    float2 ph1 = phv[r + 1];
                    float2 wv;   // real parts of the two adjacent output pixels
                    wv.x = D[A][Bq][r][0] + sS * S[r][0]
                         + kq * (ph0.x * Tv[r][0].x - ph0.y * Tv[r][0].y);
                    wv.y = D[A][Bq][r][1] + sS * S[r][1]
                         + kq * (ph1.x * Tv[r][1].x - ph1.y * Tv[r][1].y);
                    size_t fi = obase + (size_t)((nrow + r) * 256 + mcol);
                    if (fi + 2 <= (size_t)out_floats)       // defensive: never write past d_out
                        *(float2*)&outf[fi] = wv;
                }
            }
        }
    }
}

extern "C" void kernel_launch(void* const* d_in, const int* in_sizes, int n_in,
                              void* d_out, int out_size, void* d_ws, size_t ws_size,
                              hipStream_t stream)
{
    const float* s     = (const float*)d_in[0];
    const float* image = (const float*)d_in[1];
    float*       outf  = (float*)d_out;
    hipLaunchKernelGGL(fused_kernel, dim3(256), dim3(1024), 0, stream,
                       s, image, outf, out_size);
}

// Round 7
// 142.716 us; speedup vs baseline: 1.0581x; 1.0581x over previous
//
#include <hip/hip_runtime.h>

// out[b,n,m] = Re{ ifft2(y2) }  stored as float32 [256][256][256]
//   = D + 0.0125*(-1)^(A^B)*S + kappa*(-1)^(A+B)*Re( e^{2pi i 3(n+m)/256} * T_b[n%128,m%128] )
//   T_b[u,v] = sum_{i,j} s[b,i,j] e^{+2pi i (iu+jv)/128}   (unnormalized inverse DFT)
//   kappa = (0.05+0.05^2)/65536
// FFT: radix-2 DIF in registers (2 complex/lane), shuffle exchanges; LDS only for the
// transpose (XOR-swizzled, conflict-free at the b64 4-cycle floor). Positions are in
// bit-reversed order after DIF; phase 3 indexes T via bitrev7.

__device__ __forceinline__ float fwv(float w) {
    float sh = fmaxf(fabsf(w) - 1.0f, 0.0f);
    return 2.0f * copysignf(sh, w) - w;
}

__device__ __forceinline__ int bitrev7(int x) {
    return (int)(__builtin_bitreverse32((unsigned)x) >> 25);
}

__global__ __launch_bounds__(1024) void fused_kernel(const float* __restrict__ s,
                                                     const float* __restrict__ image,
                                                     float* __restrict__ outf,
                                                     int out_floats)
{
    __shared__ float2 A[128 * 128];   // 131,072 B; logical (R,C) stored at A[R*128 + ((C^R)&127)]

    const int tid  = threadIdx.x;
    const int lane = tid & 63;
    const int wave = tid >> 6;
    const int b    = blockIdx.x;
    const float PI_F   = 3.14159265358979323846f;
    const float TWO_PI = 6.2831853071795864769f;

    // --- stage twiddles: w_k = e^{+i * pi * (lane mod h) / h}, h = 64>>k (same for both regs) ---
    float twc[7], tws[7];
    #pragma unroll
    for (int k = 0; k < 7; ++k) {
        int h = 64 >> k;
        float th = PI_F * (float)(lane & (h - 1)) / (float)h;
        __sincosf(th, &tws[k], &twc[k]);
    }

    // DIF radix-2, inverse-DFT sign. Position p=(e<<6)|lane; output at p is X[bitrev7(p)].
#define FFT128()                                                                     \
    do {                                                                             \
        { float ar = x0r, ai = x0i, br = x1r, bi = x1i;                              \
          x0r = ar + br; x0i = ai + bi;                                              \
          float dr = ar - br, di = ai - bi;                                          \
          x1r = dr * twc[0] - di * tws[0];                                           \
          x1i = dr * tws[0] + di * twc[0]; }                                         \
        _Pragma("unroll")                                                            \
        for (int k = 1; k < 7; ++k) {                                                \
            int h = 64 >> k;                                                         \
            bool hi = (lane & h) != 0;                                               \
            float wc = twc[k], ws = tws[k];                                          \
            { float rr = __shfl_xor(x0r, h), ri = __shfl_xor(x0i, h);                \
              float sr = hi ? (rr - x0r) : (x0r + rr);                               \
              float si = hi ? (ri - x0i) : (x0i + ri);                               \
              float tr = sr * wc - si * ws, ti = sr * ws + si * wc;                  \
              x0r = hi ? tr : sr; x0i = hi ? ti : si; }                              \
            { float rr = __shfl_xor(x1r, h), ri = __shfl_xor(x1i, h);                \
              float sr = hi ? (rr - x1r) : (x1r + rr);                               \
              float si = hi ? (ri - x1i) : (x1i + ri);                               \
              float tr = sr * wc - si * ws, ti = sr * ws + si * wc;                  \
              x1r = hi ? tr : sr; x1i = hi ? ti : si; }                              \
        }                                                                            \
    } while (0)

    // --- phase 1: row FFTs (transform over j for fixed i); store transposed ---
    const float* sb = s + (size_t)b * (128 * 128);
    const int p0 = lane, p1 = 64 | lane;
    for (int t = 0; t < 8; ++t) {
        int i = (wave << 3) | t;
        float x0r = sb[i * 128 + lane],      x0i = 0.0f;
        float x1r = sb[i * 128 + 64 + lane], x1i = 0.0f;
        FFT128();
        // reg e holds R[i][v=bitrev7(p_e)]; store at logical (row=p_e, col=i)
        A[p0 * 128 + ((i ^ p0) & 127)] = make_float2(x0r, x0i);
        A[p1 * 128 + ((i ^ p1) & 127)] = make_float2(x1r, x1i);
    }
    __syncthreads();

    // --- phase 2: column FFTs, in-place per LDS row (wave-owned rows) ---
    for (int t = 0; t < 8; ++t) {
        int vp = (wave << 3) | t;                 // LDS row; actual v = bitrev7(vp)
        float2 a0 = A[vp * 128 + ((p0 ^ vp) & 127)];   // x[i=p0] = R[p0][v]
        float2 a1 = A[vp * 128 + ((p1 ^ vp) & 127)];
        float x0r = a0.x, x0i = a0.y, x1r = a1.x, x1i = a1.y;
        FFT128();
        // position pu holds T[u=bitrev7(pu)][v]; store at logical (row=vp, col=pu)
        A[vp * 128 + ((p0 ^ vp) & 127)] = make_float2(x0r, x0i);
        A[vp * 128 + ((p1 ^ vp) & 127)] = make_float2(x1r, x1i);
    }
    __syncthreads();
    // T[u][v] now lives at A[rv*128 + ((ru^rv)&127)], ru=bitrev7(u), rv=bitrev7(v)

    // --- phase 3: output (identical math to the verified r6 kernel; only T fetch changed) ---
    const float  c0    = 0.0125f;            // 0.05/4
    const float  kappa = 0.0525f / 65536.0f; // (0.05+0.05^2)/65536
    const size_t obase = (size_t)b * 65536;
    const float2* ib = (const float2*)(image + (size_t)b * 65536);  // [256 rows][128 float2]

    for (int qd = tid; qd < 4096; qd += 1024) {
        int p = qd >> 6;   // 0..63
        int q = qd & 63;   // 0..63

        float D[2][2][2][2]; // [A][B][r][c]
        #pragma unroll
        for (int Aq = 0; Aq < 2; ++Aq) {
            #pragma unroll
            for (int Bq = 0; Bq < 2; ++Bq) {
                int P = p + 64 * Aq, Q = q + 64 * Bq;
                float2 t0 = ib[(2 * P) * 128 + Q];
                float2 t1 = ib[(2 * P + 1) * 128 + Q];
                float a = t0.x, bb = t0.y, cc = t1.x, dd = t1.y;
                float wll = (a + bb + cc + dd) * 0.5f;
                float wlh = (a - bb + cc - dd) * 0.5f;
                float whl = (a + bb - cc - dd) * 0.5f;
                float whh = (a - bb - cc + dd) * 0.5f;
                float vll = fwv(wll), vlh = fwv(wlh), vhl = fwv(whl), vhh = fwv(whh);
                D[Aq][Bq][0][0] = (vll + vlh + vhl + vhh) * 0.5f;
                D[Aq][Bq][0][1] = (vll - vlh + vhl - vhh) * 0.5f;
                D[Aq][Bq][1][0] = (vll + vlh - vhl - vhh) * 0.5f;
                D[Aq][Bq][1][1] = (vll - vlh - vhl + vhh) * 0.5f;
            }
        }
        float S[2][2];
        #pragma unroll
        for (int r = 0; r < 2; ++r)
            #pragma unroll
            for (int c = 0; c < 2; ++c)
                S[r][c] = D[0][0][r][c] - D[1][0][r][c] - D[0][1][r][c] + D[1][1][r][c];

        // T[2p+r][2q+c] via bit-reversed swizzled LDS
        int ru0 = bitrev7(2 * p), ru1 = bitrev7(2 * p + 1);
        int rv0 = bitrev7(2 * q), rv1 = bitrev7(2 * q + 1);
        float2 Tv[2][2];
        Tv[0][0] = A[rv0 * 128 + ((ru0 ^ rv0) & 127)];
        Tv[0][1] = A[rv1 * 128 + ((ru0 ^ rv1) & 127)];
        Tv[1][0] = A[rv0 * 128 + ((ru1 ^ rv0) & 127)];
        Tv[1][1] = A[rv1 * 128 + ((ru1 ^ rv1) & 127)];

        float2 phv[3];
        #pragma unroll
        for (int k = 0; k < 3; ++k) {
            float ps, pc;
            __sincosf((TWO_PI * 3.0f / 256.0f) * (float)(2 * p + 2 * q + k), &ps, &pc);
            phv[k] = make_float2(pc, ps);
        }

        #pragma unroll
        for (int Aq = 0; Aq < 2; ++Aq) {
            #pragma unroll
            for (int Bq = 0; Bq < 2; ++Bq) {
                float kq = ((Aq + Bq) & 1) ? -kappa : kappa;
                float sS = ((Aq ^ Bq) & 1) ? -c0 : c0;
                int nrow = 2 * p + 128 * Aq;
                int mcol = 2 * q + 128 * Bq;
                #pragma unroll
                for (int r = 0; r < 2; ++r) {
                    float2 ph0 = phv[r];
                    float2 ph1 = phv[r + 1];
                    float2 wv;   // real parts of two adjacent output pixels
                    wv.x = D[Aq][Bq][r][0] + sS * S[r][0]
                         + kq * (ph0.x * Tv[r][0].x - ph0.y * Tv[r][0].y);
                    wv.y = D[Aq][Bq][r][1] + sS * S[r][1]
                         + kq * (ph1.x * Tv[r][1].x - ph1.y * Tv[r][1].y);
                    size_t fi = obase + (size_t)((nrow + r) * 256 + mcol);
                    if (fi + 2 <= (size_t)out_floats)
                        *(float2*)&outf[fi] = wv;
                }
            }
        }
    }
#undef FFT128
}

extern "C" void kernel_launch(void* const* d_in, const int* in_sizes, int n_in,
                              void* d_out, int out_size, void* d_ws, size_t ws_size,
                              hipStream_t stream)
{
    const float* s     = (const float*)d_in[0];
    const float* image = (const float*)d_in[1];
    float*       outf  = (float*)d_out;
    hipLaunchKernelGGL(fused_kernel, dim3(256), dim3(1024), 0, stream,
                       s, image, outf, out_size);
}

// Round 8
// 139.207 us; speedup vs baseline: 1.0847x; 1.0252x over previous
//
#include <hip/hip_runtime.h>

// out[b,n,m] = Re{ ifft2(y2) }  stored as float32 [256][256][256]
//   = D + 0.0125*(-1)^(A^B)*S + kappa*(-1)^(A+B)*Re( e^{2pi i 3(n+m)/256} * T_b[n%128,m%128] )
//   T_b[u,v] = sum_{i,j} s[b,i,j] e^{+2pi i (iu+jv)/128}
// FFT: radix-2 DIF shuffle FFT, 2 complex/lane. Phase 1 uses REAL-PACKING: rows 2t,2t+1
// share one complex FFT (64 instead of 128 row-FFTs), Hermitian-unpacked in registers.

__device__ __forceinline__ float fwv(float w) {
    float sh = fmaxf(fabsf(w) - 1.0f, 0.0f);
    return 2.0f * copysignf(sh, w) - w;
}

__device__ __forceinline__ int bitrev7(int x) {
    return (int)(__builtin_bitreverse32((unsigned)x) >> 25);
}

__global__ __launch_bounds__(1024) void fused_kernel(const float* __restrict__ s,
                                                     const float* __restrict__ image,
                                                     float* __restrict__ outf,
                                                     int out_floats)
{
    __shared__ float2 A[128 * 128];   // logical (R,C) stored at A[R*128 + ((C^R)&127)]

    const int tid  = threadIdx.x;
    const int lane = tid & 63;
    const int wave = tid >> 6;
    const int b    = blockIdx.x;
    const float PI_F   = 3.14159265358979323846f;
    const float TWO_PI = 6.2831853071795864769f;

    // stage twiddles: w_k = e^{+i*pi*(lane mod h)/h}, h = 64>>k
    float twc[7], tws[7];
    #pragma unroll
    for (int k = 0; k < 7; ++k) {
        int h = 64 >> k;
        float th = PI_F * (float)(lane & (h - 1)) / (float)h;
        __sincosf(th, &tws[k], &twc[k]);
    }

#define FFT128()                                                                     \
    do {                                                                             \
        { float ar = x0r, ai = x0i, br = x1r, bi = x1i;                              \
          x0r = ar + br; x0i = ai + bi;                                              \
          float dr = ar - br, di = ai - bi;                                          \
          x1r = dr * twc[0] - di * tws[0];                                           \
          x1i = dr * tws[0] + di * twc[0]; }                                         \
        _Pragma("unroll")                                                            \
        for (int k = 1; k < 7; ++k) {                                                \
            int h = 64 >> k;                                                         \
            bool hi = (lane & h) != 0;                                               \
            float wc = twc[k], ws = tws[k];                                          \
            { float rr = __shfl_xor(x0r, h), ri = __shfl_xor(x0i, h);                \
              float sr = hi ? (rr - x0r) : (x0r + rr);                               \
              float si = hi ? (ri - x0i) : (x0i + ri);                               \
              float tr = sr * wc - si * ws, ti = sr * ws + si * wc;                  \
              x0r = hi ? tr : sr; x0i = hi ? ti : si; }                              \
            { float rr = __shfl_xor(x1r, h), ri = __shfl_xor(x1i, h);                \
              float sr = hi ? (rr - x1r) : (x1r + rr);                               \
              float si = hi ? (ri - x1i) : (x1i + ri);                               \
              float tr = sr * wc - si * ws, ti = sr * ws + si * wc;                  \
              x1r = hi ? tr : sr; x1i = hi ? ti : si; }                              \
        }                                                                            \
    } while (0)

    const float* sb = s + (size_t)b * (128 * 128);
    const int p0 = lane, p1 = 64 | lane;

    // Hermitian-partner lanes in bit-reversed position space:
    //   reg0 (v even): partner lane = rev6((64 - rev6(lane)) & 63)  [v=0,64 are self]
    //   reg1 (v odd):  partner lane = lane ^ 63
    const int m6   = (int)(__builtin_bitreverse32((unsigned)lane) >> 26);
    const int prt0 = (int)(__builtin_bitreverse32((unsigned)((64 - m6) & 63)) >> 26);

    // --- phase 1: 64 real-packed row FFTs: z = s[2t'] + i*s[2t'+1] ---
    #pragma unroll 2
    for (int t = 0; t < 4; ++t) {
        int ia = (wave << 3) | (t << 1);
        int ib = ia | 1;
        float x0r = sb[ia * 128 + lane];
        float x0i = sb[ib * 128 + lane];
        float x1r = sb[ia * 128 + 64 + lane];
        float x1i = sb[ib * 128 + 64 + lane];
        FFT128();
        // unpack: R_a = (Z + conj(Zp))/2 ; R_b = (Z - conj(Zp))/(2i)
        float c0r = __shfl(x0r, prt0), c0i = __shfl(x0i, prt0);
        float a0r = 0.5f * (x0r + c0r), a0i = 0.5f * (x0i - c0i);
        float b0r = 0.5f * (x0i + c0i), b0i = 0.5f * (c0r - x0r);
        float c1r = __shfl_xor(x1r, 63), c1i = __shfl_xor(x1i, 63);
        float a1r = 0.5f * (x1r + c1r), a1i = 0.5f * (x1i - c1i);
        float b1r = 0.5f * (x1i + c1i), b1i = 0.5f * (c1r - x1r);
        A[p0 * 128 + ((ia ^ p0) & 127)] = make_float2(a0r, a0i);
        A[p0 * 128 + ((ib ^ p0) & 127)] = make_float2(b0r, b0i);
        A[p1 * 128 + ((ia ^ p1) & 127)] = make_float2(a1r, a1i);
        A[p1 * 128 + ((ib ^ p1) & 127)] = make_float2(b1r, b1i);
    }
    __syncthreads();

    // --- phase 2: column FFTs, in-place per LDS row (wave-owned) ---
    #pragma unroll 2
    for (int t = 0; t < 8; ++t) {
        int vp = (wave << 3) | t;                      // LDS row; actual v = bitrev7(vp)
        float2 a0 = A[vp * 128 + ((p0 ^ vp) & 127)];
        float2 a1 = A[vp * 128 + ((p1 ^ vp) & 127)];
        float x0r = a0.x, x0i = a0.y, x1r = a1.x, x1i = a1.y;
        FFT128();
        A[vp * 128 + ((p0 ^ vp) & 127)] = make_float2(x0r, x0i);
        A[vp * 128 + ((p1 ^ vp) & 127)] = make_float2(x1r, x1i);
    }
    __syncthreads();
    // T[u][v] at A[rv*128 + ((ru^rv)&127)], ru=bitrev7(u), rv=bitrev7(v)

    // --- phase 3: identical to verified r7 kernel ---
    const float  c0    = 0.0125f;
    const float  kappa = 0.0525f / 65536.0f;
    const size_t obase = (size_t)b * 65536;
    const float2* ib2 = (const float2*)(image + (size_t)b * 65536);

    for (int qd = tid; qd < 4096; qd += 1024) {
        int p = qd >> 6;
        int q = qd & 63;

        float D[2][2][2][2];
        #pragma unroll
        for (int Aq = 0; Aq < 2; ++Aq) {
            #pragma unroll
            for (int Bq = 0; Bq < 2; ++Bq) {
                int P = p + 64 * Aq, Q = q + 64 * Bq;
                float2 t0 = ib2[(2 * P) * 128 + Q];
                float2 t1 = ib2[(2 * P + 1) * 128 + Q];
                float a = t0.x, bb = t0.y, cc = t1.x, dd = t1.y;
                float wll = (a + bb + cc + dd) * 0.5f;
                float wlh = (a - bb + cc - dd) * 0.5f;
                float whl = (a + bb - cc - dd) * 0.5f;
                float whh = (a - bb - cc + dd) * 0.5f;
                float vll = fwv(wll), vlh = fwv(wlh), vhl = fwv(whl), vhh = fwv(whh);
                D[Aq][Bq][0][0] = (vll + vlh + vhl + vhh) * 0.5f;
                D[Aq][Bq][0][1] = (vll - vlh + vhl - vhh) * 0.5f;
                D[Aq][Bq][1][0] = (vll + vlh - vhl - vhh) * 0.5f;
                D[Aq][Bq][1][1] = (vll - vlh - vhl + vhh) * 0.5f;
            }
        }
        float S[2][2];
        #pragma unroll
        for (int r = 0; r < 2; ++r)
            #pragma unroll
            for (int c = 0; c < 2; ++c)
                S[r][c] = D[0][0][r][c] - D[1][0][r][c] - D[0][1][r][c] + D[1][1][r][c];

        int ru0 = bitrev7(2 * p), ru1 = bitrev7(2 * p + 1);
        int rv0 = bitrev7(2 * q), rv1 = bitrev7(2 * q + 1);
        float2 Tv[2][2];
        Tv[0][0] = A[rv0 * 128 + ((ru0 ^ rv0) & 127)];
        Tv[0][1] = A[rv1 * 128 + ((ru0 ^ rv1) & 127)];
        Tv[1][0] = A[rv0 * 128 + ((ru1 ^ rv0) & 127)];
        Tv[1][1] = A[rv1 * 128 + ((ru1 ^ rv1) & 127)];

        float2 phv[3];
        #pragma unroll
        for (int k = 0; k < 3; ++k) {
            float ps, pc;
            __sincosf((TWO_PI * 3.0f / 256.0f) * (float)(2 * p + 2 * q + k), &ps, &pc);
            phv[k] = make_float2(pc, ps);
        }

        #pragma unroll
        for (int Aq = 0; Aq < 2; ++Aq) {
            #pragma unroll
            for (int Bq = 0; Bq < 2; ++Bq) {
                float kq = ((Aq + Bq) & 1) ? -kappa : kappa;
                float sS = ((Aq ^ Bq) & 1) ? -c0 : c0;
                int nrow = 2 * p + 128 * Aq;
                int mcol = 2 * q + 128 * Bq;
                #pragma unroll
                for (int r = 0; r < 2; ++r) {
                    float2 ph0 = phv[r];
                    float2 ph1 = phv[r + 1];
                    float2 wv;
                    wv.x = D[Aq][Bq][r][0] + sS * S[r][0]
                         + kq * (ph0.x * Tv[r][0].x - ph0.y * Tv[r][0].y);
                    wv.y = D[Aq][Bq][r][1] + sS * S[r][1]
                         + kq * (ph1.x * Tv[r][1].x - ph1.y * Tv[r][1].y);
                    size_t fi = obase + (size_t)((nrow + r) * 256 + mcol);
                    if (fi + 2 <= (size_t)out_floats)
                        *(float2*)&outf[fi] = wv;
                }
            }
        }
    }
#undef FFT128
}

extern "C" void kernel_launch(void* const* d_in, const int* in_sizes, int n_in,
                              void* d_out, int out_size, void* d_ws, size_t ws_size,
                              hipStream_t stream)
{
    const float* s     = (const float*)d_in[0];
    const float* image = (const float*)d_in[1];
    float*       outf  = (float*)d_out;
    hipLaunchKernelGGL(fused_kernel, dim3(256), dim3(1024), 0, stream,
                       s, image, outf, out_size);
}

// Round 9
// 138.761 us; speedup vs baseline: 1.0882x; 1.0032x over previous
//
#include <hip/hip_runtime.h>

// out[b,n,m] = Re{ ifft2(y2) }  stored as float32 [256][256][256]
//   = D + 0.0125*(-1)^(A^B)*S + kappa*(-1)^(A+B)*Re( e^{2pi i 3(n+m)/256} * T_b[n%128,m%128] )
//   T_b[u,v] = sum_{i,j} s[b,i,j] e^{+2pi i (iu+jv)/128}
// FFT: radix-2 DIF shuffle FFT, 2 complex/lane; phase 1 real-packs row pairs.
// R9: image prefetched to registers before the FFT (latency hidden under it);
//     phase-3 e^{i*3*2pi*t/256} from a 256-entry LDS table; no store guard.

__device__ __forceinline__ float fwv(float w) {
    float sh = fmaxf(fabsf(w) - 1.0f, 0.0f);
    return 2.0f * copysignf(sh, w) - w;
}

__device__ __forceinline__ int bitrev7(int x) {
    return (int)(__builtin_bitreverse32((unsigned)x) >> 25);
}

__global__ __launch_bounds__(1024, 4) void fused_kernel(const float* __restrict__ s,
                                                        const float* __restrict__ image,
                                                        float* __restrict__ outf)
{
    __shared__ float2 A[128 * 128];   // logical (R,C) at A[R*128 + ((C^R)&127)]
    __shared__ float2 ph_tab[256];    // e^{+2pi i 3 t/256}

    const int tid  = threadIdx.x;
    const int lane = tid & 63;
    const int wave = tid >> 6;
    const int b    = blockIdx.x;
    const float PI_F   = 3.14159265358979323846f;
    const float TWO_PI = 6.2831853071795864769f;

    // --- prefetch this thread's 32 image float2 (its 4 quadruples) into registers ---
    const float2* ib2 = (const float2*)(image + (size_t)b * 65536);  // [256][128] float2
    const int q  = tid & 63;     // phase-3 q (fixed per thread)
    const int pw = tid >> 6;     // phase-3 p low bits
    float2 img[4][8];
    #pragma unroll
    for (int it = 0; it < 4; ++it) {
        int p = (it << 4) | pw;
        #pragma unroll
        for (int Aq = 0; Aq < 2; ++Aq)
            #pragma unroll
            for (int Bq = 0; Bq < 2; ++Bq)
                #pragma unroll
                for (int r = 0; r < 2; ++r)
                    img[it][(Aq << 2) | (Bq << 1) | r] =
                        ib2[(2 * (p + 64 * Aq) + r) * 128 + (q + 64 * Bq)];
    }

    // --- phase table (covered by the phase-1 barrier) ---
    if (tid < 256) {
        float ps, pc;
        __sincosf((TWO_PI * 3.0f / 256.0f) * (float)tid, &ps, &pc);
        ph_tab[tid] = make_float2(pc, ps);
    }

    // stage twiddles: w_k = e^{+i*pi*(lane mod h)/h}, h = 64>>k
    float twc[7], tws[7];
    #pragma unroll
    for (int k = 0; k < 7; ++k) {
        int h = 64 >> k;
        float th = PI_F * (float)(lane & (h - 1)) / (float)h;
        __sincosf(th, &tws[k], &twc[k]);
    }

#define FFT128()                                                                     \
    do {                                                                             \
        { float ar = x0r, ai = x0i, br = x1r, bi = x1i;                              \
          x0r = ar + br; x0i = ai + bi;                                              \
          float dr = ar - br, di = ai - bi;                                          \
          x1r = dr * twc[0] - di * tws[0];                                           \
          x1i = dr * tws[0] + di * twc[0]; }                                         \
        _Pragma("unroll")                                                            \
        for (int k = 1; k < 7; ++k) {                                                \
            int h = 64 >> k;                                                         \
            bool hi = (lane & h) != 0;                                               \
            float wc = twc[k], ws = tws[k];                                          \
            { float rr = __shfl_xor(x0r, h), ri = __shfl_xor(x0i, h);                \
              float sr = hi ? (rr - x0r) : (x0r + rr);                               \
              float si = hi ? (ri - x0i) : (x0i + ri);                               \
              float tr = sr * wc - si * ws, ti = sr * ws + si * wc;                  \
              x0r = hi ? tr : sr; x0i = hi ? ti : si; }                              \
            { float rr = __shfl_xor(x1r, h), ri = __shfl_xor(x1i, h);                \
              float sr = hi ? (rr - x1r) : (x1r + rr);                               \
              float si = hi ? (ri - x1i) : (x1i + ri);                               \
              float tr = sr * wc - si * ws, ti = sr * ws + si * wc;                  \
              x1r = hi ? tr : sr; x1i = hi ? ti : si; }                              \
        }                                                                            \
    } while (0)

    const float* sb = s + (size_t)b * (128 * 128);
    const int p0 = lane, p1 = 64 | lane;

    // Hermitian-partner lanes in bit-reversed position space
    const int m6   = (int)(__builtin_bitreverse32((unsigned)lane) >> 26);
    const int prt0 = (int)(__builtin_bitreverse32((unsigned)((64 - m6) & 63)) >> 26);

    // --- phase 1: 64 real-packed row FFTs: z = s[2t'] + i*s[2t'+1] ---
    #pragma unroll 2
    for (int t = 0; t < 4; ++t) {
        int ia = (wave << 3) | (t << 1);
        int ic = ia | 1;
        float x0r = sb[ia * 128 + lane];
        float x0i = sb[ic * 128 + lane];
        float x1r = sb[ia * 128 + 64 + lane];
        float x1i = sb[ic * 128 + 64 + lane];
        FFT128();
        float c0r = __shfl(x0r, prt0), c0i = __shfl(x0i, prt0);
        float a0r = 0.5f * (x0r + c0r), a0i = 0.5f * (x0i - c0i);
        float b0r = 0.5f * (x0i + c0i), b0i = 0.5f * (c0r - x0r);
        float c1r = __shfl_xor(x1r, 63), c1i = __shfl_xor(x1i, 63);
        float a1r = 0.5f * (x1r + c1r), a1i = 0.5f * (x1i - c1i);
        float b1r = 0.5f * (x1i + c1i), b1i = 0.5f * (c1r - x1r);
        A[p0 * 128 + ((ia ^ p0) & 127)] = make_float2(a0r, a0i);
        A[p0 * 128 + ((ic ^ p0) & 127)] = make_float2(b0r, b0i);
        A[p1 * 128 + ((ia ^ p1) & 127)] = make_float2(a1r, a1i);
        A[p1 * 128 + ((ic ^ p1) & 127)] = make_float2(b1r, b1i);
    }
    __syncthreads();

    // --- phase 2: column FFTs, in-place per LDS row (wave-owned) ---
    #pragma unroll 2
    for (int t = 0; t < 8; ++t) {
        int vp = (wave << 3) | t;                      // LDS row; actual v = bitrev7(vp)
        float2 a0 = A[vp * 128 + ((p0 ^ vp) & 127)];
        float2 a1 = A[vp * 128 + ((p1 ^ vp) & 127)];
        float x0r = a0.x, x0i = a0.y, x1r = a1.x, x1i = a1.y;
        FFT128();
        A[vp * 128 + ((p0 ^ vp) & 127)] = make_float2(x0r, x0i);
        A[vp * 128 + ((p1 ^ vp) & 127)] = make_float2(x1r, x1i);
    }
    __syncthreads();
    // T[u][v] at A[rv*128 + ((ru^rv)&127)], ru=bitrev7(u), rv=bitrev7(v)

    // --- phase 3: all image data already in registers ---
    const float  c0    = 0.0125f;
    const float  kappa = 0.0525f / 65536.0f;
    const size_t obase = (size_t)b * 65536;
    const int rv0 = bitrev7(2 * q), rv1 = bitrev7(2 * q + 1);

    #pragma unroll
    for (int it = 0; it < 4; ++it) {
        int p = (it << 4) | pw;

        float D[2][2][2][2];
        #pragma unroll
        for (int Aq = 0; Aq < 2; ++Aq) {
            #pragma unroll
            for (int Bq = 0; Bq < 2; ++Bq) {
                float2 t0 = img[it][(Aq << 2) | (Bq << 1)];
                float2 t1 = img[it][(Aq << 2) | (Bq << 1) | 1];
                float a = t0.x, bb = t0.y, cc = t1.x, dd = t1.y;
                float wll = (a + bb + cc + dd) * 0.5f;
                float wlh = (a - bb + cc - dd) * 0.5f;
                float whl = (a + bb - cc - dd) * 0.5f;
                float whh = (a - bb - cc + dd) * 0.5f;
                float vll = fwv(wll), vlh = fwv(wlh), vhl = fwv(whl), vhh = fwv(whh);
                D[Aq][Bq][0][0] = (vll + vlh + vhl + vhh) * 0.5f;
                D[Aq][Bq][0][1] = (vll - vlh + vhl - vhh) * 0.5f;
                D[Aq][Bq][1][0] = (vll + vlh - vhl - vhh) * 0.5f;
                D[Aq][Bq][1][1] = (vll - vlh - vhl + vhh) * 0.5f;
            }
        }
        float S[2][2];
        #pragma unroll
        for (int r = 0; r < 2; ++r)
            #pragma unroll
            for (int c = 0; c < 2; ++c)
                S[r][c] = D[0][0][r][c] - D[1][0][r][c] - D[0][1][r][c] + D[1][1][r][c];

        int ru0 = bitrev7(2 * p), ru1 = bitrev7(2 * p + 1);
        float2 Tv[2][2];
        Tv[0][0] = A[rv0 * 128 + ((ru0 ^ rv0) & 127)];
        Tv[0][1] = A[rv1 * 128 + ((ru0 ^ rv1) & 127)];
        Tv[1][0] = A[rv0 * 128 + ((ru1 ^ rv0) & 127)];
        Tv[1][1] = A[rv1 * 128 + ((ru1 ^ rv1) & 127)];

        int tbase = 2 * p + 2 * q;          // <= 254
        float2 phv[3] = { ph_tab[tbase], ph_tab[tbase + 1], ph_tab[tbase + 2] };

        #pragma unroll
        for (int Aq = 0; Aq < 2; ++Aq) {
            #pragma unroll
            for (int Bq = 0; Bq < 2; ++Bq) {
                float kq = ((Aq + Bq) & 1) ? -kappa : kappa;
                float sS = ((Aq ^ Bq) & 1) ? -c0 : c0;
                int nrow = 2 * p + 128 * Aq;
                int mcol = 2 * q + 128 * Bq;
                #pragma unroll
                for (int r = 0; r < 2; ++r) {
                    float2 ph0 = phv[r];
                    float2 ph1 = phv[r + 1];
                    float2 wv;
                    wv.x = D[Aq][Bq][r][0] + sS * S[r][0]
                         + kq * (ph0.x * Tv[r][0].x - ph0.y * Tv[r][0].y);
                    wv.y = D[Aq][Bq][r][1] + sS * S[r][1]
                         + kq * (ph1.x * Tv[r][1].x - ph1.y * Tv[r][1].y);
                    *(float2*)&outf[obase + (size_t)((nrow + r) * 256 + mcol)] = wv;
                }
            }
        }
    }
#undef FFT128
}

extern "C" void kernel_launch(void* const* d_in, const int* in_sizes, int n_in,
                              void* d_out, int out_size, void* d_ws, size_t ws_size,
                              hipStream_t stream)
{
    const float* s     = (const float*)d_in[0];
    const float* image = (const float*)d_in[1];
    float*       outf  = (float*)d_out;
    hipLaunchKernelGGL(fused_kernel, dim3(256), dim3(1024), 0, stream,
                       s, image, outf);
}

// Round 10
// 133.948 us; speedup vs baseline: 1.1273x; 1.0359x over previous
//
#include <hip/hip_runtime.h>

// out[b,n,m] = Re{ ifft2(y2) } stored float32 [256][256][256]
//   = D + 0.0125*(-1)^(A^B)*S + kappa*(-1)^(A+B)*Re( e^{2pi i 3(n+m)/256} * T_b[n%128,m%128] )
//   T_b[u,v] = sum_{i,j} s[b,i,j] e^{+2pi i (iu+jv)/128},  kappa=(0.05+0.05^2)/65536
// R10: Hermitian phase 2 (real s => T[u][v]=conj(T[(128-u)%128][128-v]); only v=0..64
// computed, v=0/64 packed into one real-pair FFT). Prefetched image consumed into
// base=D+sS*S right after phase 1 (short live range so the loads stay early).

__device__ __forceinline__ float fwv(float w) {
    float sh = fmaxf(fabsf(w) - 1.0f, 0.0f);
    return 2.0f * copysignf(sh, w) - w;
}
__device__ __forceinline__ int bitrev7(int x) {
    return (int)(__builtin_bitreverse32((unsigned)x) >> 25);
}

__global__ __launch_bounds__(1024, 4) void fused_kernel(const float* __restrict__ s,
                                                        const float* __restrict__ image,
                                                        float* __restrict__ outf)
{
    __shared__ float2 A[128 * 128];   // logical (R,C) at A[R*128 + ((C^R)&127)]
    __shared__ float2 ph_tab[256];    // e^{+2pi i 3 t/256}

    const int tid  = threadIdx.x;
    const int lane = tid & 63;
    const int wave = tid >> 6;
    const int b    = blockIdx.x;
    const float PI_F   = 3.14159265358979323846f;
    const float TWO_PI = 6.2831853071795864769f;

    // ---- issue image loads for it=0,1 (consumed right after phase 1) ----
    const float2* ib2 = (const float2*)(image + (size_t)b * 65536);  // [256][128]
    const int q  = lane;
    const int pw = wave;
    float2 img01[2][8];
    #pragma unroll
    for (int it = 0; it < 2; ++it) {
        int p = (it << 4) | pw;
        #pragma unroll
        for (int Aq = 0; Aq < 2; ++Aq)
            #pragma unroll
            for (int Bq = 0; Bq < 2; ++Bq)
                #pragma unroll
                for (int r = 0; r < 2; ++r)
                    img01[it][(Aq << 2) | (Bq << 1) | r] =
                        ib2[(2 * (p + 64 * Aq) + r) * 128 + (q + 64 * Bq)];
    }

    if (tid < 256) {
        float ps, pc;
        __sincosf((TWO_PI * 3.0f / 256.0f) * (float)tid, &ps, &pc);
        ph_tab[tid] = make_float2(pc, ps);
    }

    // stage twiddles: w_k = e^{+i*pi*(lane mod h)/h}, h = 64>>k
    float twc[7], tws[7];
    #pragma unroll
    for (int k = 0; k < 7; ++k) {
        int h = 64 >> k;
        float th = PI_F * (float)(lane & (h - 1)) / (float)h;
        __sincosf(th, &tws[k], &twc[k]);
    }

#define FFT128()                                                                     \
    do {                                                                             \
        { float ar = x0r, ai = x0i, br = x1r, bi = x1i;                              \
          x0r = ar + br; x0i = ai + bi;                                              \
          float dr = ar - br, di = ai - bi;                                          \
          x1r = dr * twc[0] - di * tws[0];                                           \
          x1i = dr * tws[0] + di * twc[0]; }                                         \
        _Pragma("unroll")                                                            \
        for (int k = 1; k < 7; ++k) {                                                \
            int h = 64 >> k;                                                         \
            bool hi = (lane & h) != 0;                                               \
            float wc = twc[k], ws = tws[k];                                          \
            { float rr = __shfl_xor(x0r, h), ri = __shfl_xor(x0i, h);                \
              float sr = hi ? (rr - x0r) : (x0r + rr);                               \
              float si = hi ? (ri - x0i) : (x0i + ri);                               \
              float tr = sr * wc - si * ws, ti = sr * ws + si * wc;                  \
              x0r = hi ? tr : sr; x0i = hi ? ti : si; }                              \
            { float rr = __shfl_xor(x1r, h), ri = __shfl_xor(x1i, h);                \
              float sr = hi ? (rr - x1r) : (x1r + rr);                               \
              float si = hi ? (ri - x1i) : (x1i + ri);                               \
              float tr = sr * wc - si * ws, ti = sr * ws + si * wc;                  \
              x1r = hi ? tr : sr; x1i = hi ? ti : si; }                              \
        }                                                                            \
    } while (0)

    const float* sb = s + (size_t)b * (128 * 128);
    const int p0 = lane, p1 = 64 | lane;

    // Hermitian-partner lanes in bit-reversed position space
    const int m6   = (int)(__builtin_bitreverse32((unsigned)lane) >> 26);
    const int prt0 = (int)(__builtin_bitreverse32((unsigned)((64 - m6) & 63)) >> 26);

    // phase 2 reads only even rows (v<64) + row 1 (v=64): predicate phase-1 stores
    const bool st0 = ((lane & 1) == 0) || (lane == 1);   // position p0 = lane
    const bool st1 = ((lane & 1) == 0);                  // position p1 = 64|lane

    // --- phase 1: 64 real-packed row FFTs: z = s[2t'] + i*s[2t'+1] ---
    #pragma unroll 2
    for (int t = 0; t < 4; ++t) {
        int ia = (wave << 3) | (t << 1);
        int ic = ia | 1;
        float x0r = sb[ia * 128 + lane];
        float x0i = sb[ic * 128 + lane];
        float x1r = sb[ia * 128 + 64 + lane];
        float x1i = sb[ic * 128 + 64 + lane];
        FFT128();
        float c0r = __shfl(x0r, prt0), c0i = __shfl(x0i, prt0);
        float a0r = 0.5f * (x0r + c0r), a0i = 0.5f * (x0i - c0i);
        float b0r = 0.5f * (x0i + c0i), b0i = 0.5f * (c0r - x0r);
        float c1r = __shfl_xor(x1r, 63), c1i = __shfl_xor(x1i, 63);
        float a1r = 0.5f * (x1r + c1r), a1i = 0.5f * (x1i - c1i);
        float b1r = 0.5f * (x1i + c1i), b1i = 0.5f * (c1r - x1r);
        if (st0) {
            A[p0 * 128 + ((ia ^ p0) & 127)] = make_float2(a0r, a0i);
            A[p0 * 128 + ((ic ^ p0) & 127)] = make_float2(b0r, b0i);
        }
        if (st1) {
            A[p1 * 128 + ((ia ^ p1) & 127)] = make_float2(a1r, a1i);
            A[p1 * 128 + ((ic ^ p1) & 127)] = make_float2(b1r, b1i);
        }
    }
    __syncthreads();

    // --- early Haar for it=0,1: base = D + sS*S (frees img01; short live range) ---
    const float c0c = 0.0125f;
    float2 base01[2][2][2][2];   // [it][Aq][Bq][r]; .x = col c=0, .y = col c=1
    #pragma unroll
    for (int it = 0; it < 2; ++it) {
        float D[2][2][2][2];
        #pragma unroll
        for (int Aq = 0; Aq < 2; ++Aq)
            #pragma unroll
            for (int Bq = 0; Bq < 2; ++Bq) {
                float2 t0 = img01[it][(Aq << 2) | (Bq << 1)];
                float2 t1 = img01[it][(Aq << 2) | (Bq << 1) | 1];
                float a = t0.x, bb = t0.y, cc = t1.x, dd = t1.y;
                float wll = (a + bb + cc + dd) * 0.5f;
                float wlh = (a - bb + cc - dd) * 0.5f;
                float whl = (a + bb - cc - dd) * 0.5f;
                float whh = (a - bb - cc + dd) * 0.5f;
                float vll = fwv(wll), vlh = fwv(wlh), vhl = fwv(whl), vhh = fwv(whh);
                D[Aq][Bq][0][0] = (vll + vlh + vhl + vhh) * 0.5f;
                D[Aq][Bq][0][1] = (vll - vlh + vhl - vhh) * 0.5f;
                D[Aq][Bq][1][0] = (vll + vlh - vhl - vhh) * 0.5f;
                D[Aq][Bq][1][1] = (vll - vlh - vhl + vhh) * 0.5f;
            }
        #pragma unroll
        for (int r = 0; r < 2; ++r) {
            float S0 = D[0][0][r][0] - D[1][0][r][0] - D[0][1][r][0] + D[1][1][r][0];
            float S1 = D[0][0][r][1] - D[1][0][r][1] - D[0][1][r][1] + D[1][1][r][1];
            #pragma unroll
            for (int Aq = 0; Aq < 2; ++Aq)
                #pragma unroll
                for (int Bq = 0; Bq < 2; ++Bq) {
                    float sS = ((Aq ^ Bq) & 1) ? -c0c : c0c;
                    base01[it][Aq][Bq][r] =
                        make_float2(D[Aq][Bq][r][0] + sS * S0, D[Aq][Bq][r][1] + sS * S1);
                }
        }
    }

    // --- phase 2: Hermitian column FFTs — only v = 0..64 (even rows; v=0,64 packed) ---
    #pragma unroll 2
    for (int t = 0; t < 4; ++t) {
        int vp = (wave << 3) | (t << 1);            // even row; v = bitrev7(vp) < 64
        if (vp == 0) {
            // packed: z_i = R[i][0] + i*R[i][64]  (both columns real)
            float x0r = A[p0].x, x0i = A[128 + (p0 ^ 1)].x;
            float x1r = A[p1].x, x1i = A[128 + (p1 ^ 1)].x;
            FFT128();
            float c0r = __shfl(x0r, prt0), c0i = __shfl(x0i, prt0);
            float T0r = 0.5f * (x0r + c0r), T0i = 0.5f * (x0i - c0i);   // T[.][0]
            float S0r = 0.5f * (x0i + c0i), S0i = 0.5f * (c0r - x0r);   // T[.][64]
            float c1r = __shfl_xor(x1r, 63), c1i = __shfl_xor(x1i, 63);
            float T1r = 0.5f * (x1r + c1r), T1i = 0.5f * (x1i - c1i);
            float S1r = 0.5f * (x1i + c1i), S1i = 0.5f * (c1r - x1r);
            A[p0] = make_float2(T0r, T0i);
            A[p1] = make_float2(T1r, T1i);
            A[128 + (p0 ^ 1)] = make_float2(S0r, S0i);
            A[128 + (p1 ^ 1)] = make_float2(S1r, S1i);
        } else {
            float2 a0 = A[vp * 128 + ((p0 ^ vp) & 127)];
            float2 a1 = A[vp * 128 + ((p1 ^ vp) & 127)];
            float x0r = a0.x, x0i = a0.y, x1r = a1.x, x1i = a1.y;
            FFT128();
            A[vp * 128 + ((p0 ^ vp) & 127)] = make_float2(x0r, x0i);
            A[vp * 128 + ((p1 ^ vp) & 127)] = make_float2(x1r, x1i);
        }
    }
    __syncthreads();
    // T[u][v] (v<=64) at A[rv*128 + ((ru^rv)&127)], ru=bitrev7(u), rv=bitrev7(v);
    // v>=65: T[u][v] = conj( T[(128-u)%128][128-v] )

    // --- issue it=2,3 image loads now; they fly under it=0,1 emission ---
    float2 img23[2][8];
    #pragma unroll
    for (int it = 0; it < 2; ++it) {
        int p = ((it + 2) << 4) | pw;
        #pragma unroll
        for (int Aq = 0; Aq < 2; ++Aq)
            #pragma unroll
            for (int Bq = 0; Bq < 2; ++Bq)
                #pragma unroll
                for (int r = 0; r < 2; ++r)
                    img23[it][(Aq << 2) | (Bq << 1) | r] =
                        ib2[(2 * (p + 64 * Aq) + r) * 128 + (q + 64 * Bq)];
    }

    const float  kappa = 0.0525f / 65536.0f;
    const size_t obase = (size_t)b * 65536;

    const int  v0c = 2 * q, v1c = 2 * q + 1;
    const bool f0 = v0c > 64, f1 = v1c > 64;
    const int  rv0 = bitrev7(f0 ? 128 - v0c : v0c);
    const int  rv1 = bitrev7(f1 ? 128 - v1c : v1c);
    const float sg0 = f0 ? -1.0f : 1.0f;
    const float sg1 = f1 ? -1.0f : 1.0f;

    auto emit = [&](int p, const float2 (&bse)[2][2][2]) {
        float2 Tv[2][2];
        #pragma unroll
        for (int r = 0; r < 2; ++r) {
            int u   = 2 * p + r;
            int ruD = bitrev7(u);
            int ruC = bitrev7((128 - u) & 127);
            float2 t0 = A[rv0 * 128 + (((f0 ? ruC : ruD) ^ rv0) & 127)];
            float2 t1 = A[rv1 * 128 + (((f1 ? ruC : ruD) ^ rv1) & 127)];
            Tv[r][0] = make_float2(t0.x, sg0 * t0.y);
            Tv[r][1] = make_float2(t1.x, sg1 * t1.y);
        }
        int tb = 2 * p + 2 * q;
        float2 phv[3] = { ph_tab[tb], ph_tab[tb + 1], ph_tab[tb + 2] };
        #pragma unroll
        for (int Aq = 0; Aq < 2; ++Aq)
            #pragma unroll
            for (int Bq = 0; Bq < 2; ++Bq) {
                float kq = ((Aq + Bq) & 1) ? -kappa : kappa;
                int nrow = 2 * p + 128 * Aq;
                int mcol = 2 * q + 128 * Bq;
                #pragma unroll
                for (int r = 0; r < 2; ++r) {
                    float2 ph0 = phv[r], ph1 = phv[r + 1];
                    float2 wv;
                    wv.x = bse[Aq][Bq][r].x + kq * (ph0.x * Tv[r][0].x - ph0.y * Tv[r][0].y);
                    wv.y = bse[Aq][Bq][r].y + kq * (ph1.x * Tv[r][1].x - ph1.y * Tv[r][1].y);
                    *(float2*)&outf[obase + (size_t)((nrow + r) * 256 + mcol)] = wv;
                }
            }
    };

    emit((0 << 4) | pw, base01[0]);
    emit((1 << 4) | pw, base01[1]);

    #pragma unroll
    for (int it = 0; it < 2; ++it) {
        float D[2][2][2][2];
        #pragma unroll
        for (int Aq = 0; Aq < 2; ++Aq)
            #pragma unroll
            for (int Bq = 0; Bq < 2; ++Bq) {
                float2 t0 = img23[it][(Aq << 2) | (Bq << 1)];
                float2 t1 = img23[it][(Aq << 2) | (Bq << 1) | 1];
                float a = t0.x, bb = t0.y, cc = t1.x, dd = t1.y;
                float wll = (a + bb + cc + dd) * 0.5f;
                float wlh = (a - bb + cc - dd) * 0.5f;
                float whl = (a + bb - cc - dd) * 0.5f;
                float whh = (a - bb - cc + dd) * 0.5f;
                float vll = fwv(wll), vlh = fwv(wlh), vhl = fwv(whl), vhh = fwv(whh);
                D[Aq][Bq][0][0] = (vll + vlh + vhl + vhh) * 0.5f;
                D[Aq][Bq][0][1] = (vll - vlh + vhl - vhh) * 0.5f;
                D[Aq][Bq][1][0] = (vll + vlh - vhl - vhh) * 0.5f;
                D[Aq][Bq][1][1] = (vll - vlh - vhl + vhh) * 0.5f;
            }
        float2 bse[2][2][2];
        #pragma unroll
        for (int r = 0; r < 2; ++r) {
            float S0 = D[0][0][r][0] - D[1][0][r][0] - D[0][1][r][0] + D[1][1][r][0];
            float S1 = D[0][0][r][1] - D[1][0][r][1] - D[0][1][r][1] + D[1][1][r][1];
            #pragma unroll
            for (int Aq = 0; Aq < 2; ++Aq)
                #pragma unroll
                for (int Bq = 0; Bq < 2; ++Bq) {
                    float sS = ((Aq ^ Bq) & 1) ? -c0c : c0c;
                    bse[Aq][Bq][r] =
                        make_float2(D[Aq][Bq][r][0] + sS * S0, D[Aq][Bq][r][1] + sS * S1);
                }
        }
        emit(((it + 2) << 4) | pw, bse);
    }
#undef FFT128
}

extern "C" void kernel_launch(void* const* d_in, const int* in_sizes, int n_in,
                              void* d_out, int out_size, void* d_ws, size_t ws_size,
                              hipStream_t stream)
{
    const float* s     = (const float*)d_in[0];
    const float* image = (const float*)d_in[1];
    float*       outf  = (float*)d_out;
    hipLaunchKernelGGL(fused_kernel, dim3(256), dim3(1024), 0, stream,
                       s, image, outf);
}